// Round 1
// baseline (243.733 us; speedup 1.0000x reference)
//
#include <hip/hip_runtime.h>

// MAMBA chunk scan — Round 5: fused-half blocks, 512 thr / 8 waves, grid 1024.
//   out[m,p] = exp(dA[m]) * ( C[m,:]@prev[p,:]^T                      (inter, K=128)
//             + sum_{k<=m} cb[m,k]*(exp(-dA[k])*dt[k]*x[k,p]) )       (intra, K<=256)
//             + D[h]*x[m,p]                                           (diag, epilogue)
// Changes vs r4 (117us rocprof, Occ 26%, all pipes idle -> latency-bound):
//  - one block per (b,c,h): x^T staged ONCE (single 33.8KB LDS buffer), prev read
//    once, ONE barrier (was 3). Grid 2048->1024.
//  - decay weight w[k]=exp(-dA[k])*dt[k] folded into the STAGED x (computed during
//    staging, 8 expf/thread) -> intra inner loop is load-cb/mask/cvt/mfma only,
//    no dA/dt loads, no expf. D-term moved to epilogue as +Dh*x[m,p] (f32 exact).
//  - triangle balanced: wave w owns 16-row tiles (w, 15-w) -> ~constant 9 intra
//    k-blocks per wave (was 1..8 skewed).
//  - inter runs BEFORE the barrier (no LDS use) -> LDS-write drain hidden.
//  - __launch_bounds__(512,6): 24 waves/CU target (3 blocks; LDS fits 4).
// B=2 S=4096 CS=256 H=32 G=1 P=64 N=128 NC=16

typedef unsigned short u16;
typedef __bf16 v8bf __attribute__((ext_vector_type(8)));
typedef unsigned short v8u16 __attribute__((ext_vector_type(8)));
typedef float v4f __attribute__((ext_vector_type(4)));

#define LDB 264  // u16 row stride = 528B; 132 dwords == 4 mod 32 -> 2-way bank floor

__device__ __forceinline__ unsigned pk2(float a, float b) {
  u16 x = __builtin_bit_cast(u16, (__bf16)a);
  u16 y = __builtin_bit_cast(u16, (__bf16)b);
  return (unsigned)x | ((unsigned)y << 16);
}
__device__ __forceinline__ v8bf cvt8(float4 lo, float4 hi) {
  v8bf r;
  r[0] = (__bf16)lo.x; r[1] = (__bf16)lo.y; r[2] = (__bf16)lo.z; r[3] = (__bf16)lo.w;
  r[4] = (__bf16)hi.x; r[5] = (__bf16)hi.y; r[6] = (__bf16)hi.z; r[7] = (__bf16)hi.w;
  return r;
}
__device__ __forceinline__ v8bf cvt8_mask(float4 lo, float4 hi, int k0, int m) {
  const float av[8] = {lo.x, lo.y, lo.z, lo.w, hi.x, hi.y, hi.z, hi.w};
  v8bf r;
#pragma unroll
  for (int j = 0; j < 8; j++) r[j] = (__bf16)((k0 + j <= m) ? av[j] : 0.f);
  return r;
}

__global__ __launch_bounds__(512, 6) void mamba_cs_kernel(
    const float* __restrict__ cbp,   // (2,16,1,256,256)
    const float* __restrict__ xp,    // (2,4096,32,64)
    const float* __restrict__ dtp,   // (2,32,16,256)
    const float* __restrict__ dAp,   // (2,32,16,256)
    const float* __restrict__ Cp,    // (2,4096,1,128)
    const float* __restrict__ pvp,   // (2,16,32,64,128)
    const float* __restrict__ Dp,    // (32,)
    float* __restrict__ outp)        // (2,4096,32,64)
{
  __shared__ u16 sB[64 * LDB];  // w-scaled x^T: [p][k], 33792B

  const int bid = blockIdx.x;
  const int h = bid & 31;
  const int c = (bid >> 5) & 15;
  const int b = bid >> 9;
  const int t = threadIdx.x;
  const int lane = t & 63;
  const int wid = t >> 6;          // 0..7
  const int row = lane & 15;
  const int q = lane >> 4;
  const int qo = q * 8;

  // paired 16-row tiles for triangle balance: wave w -> tiles (w, 15-w)
  const int Ta = wid;
  const int Tb = 15 - wid;
  const int ma = Ta * 16 + row;
  const int mb = Tb * 16 + row;

  const int base_hc = ((b * 32 + h) * 16 + c) * 256;
  const float Dh = Dp[h];

  const float* CBbase = cbp + (size_t)(b * 16 + c) * 65536;
  const float* Cbase  = Cp + (size_t)(b * 4096 + c * 256) * 128;
  const float* Pbase  = pvp + (size_t)((b * 16 + c) * 32 + h) * 8192;
  const float* Xbase  = xp + ((size_t)(b * 4096 + c * 256) * 32 + h) * 64;  // k stride 2048

  v4f acc[2][4];
#pragma unroll
  for (int i = 0; i < 2; i++)
#pragma unroll
    for (int j = 0; j < 4; j++) acc[i][j] = (v4f){0.f, 0.f, 0.f, 0.f};

  // ---- stage w-scaled x^T into LDS (once, whole 256-k tile) ----
  {
    const int pg = t & 15, kp = t >> 4;  // kp 0..31
#pragma unroll
    for (int kk = 0; kk < 4; kk++) {
      const int k0 = kk * 64 + 2 * kp;
      const float2 d2 = *(const float2*)(dAp + base_hc + k0);
      const float2 t2 = *(const float2*)(dtp + base_hc + k0);
      const float w0 = __expf(-d2.x) * t2.x;
      const float w1 = __expf(-d2.y) * t2.y;
      const float* x0 = Xbase + (size_t)k0 * 2048;
      const float* x1 = x0 + 2048;
#pragma unroll
      for (int j = 0; j < 4; j++) {
        const int p = pg + 16 * j;
        *(unsigned*)&sB[p * LDB + k0] = pk2(w0 * x0[p], w1 * x1[p]);
      }
    }
  }

  // ---- inter (no LDS use: runs before the barrier, hides LDS-write drain) ----
  {
    const float* Cra = Cbase + (size_t)ma * 128;
    const float* Crb = Cbase + (size_t)mb * 128;
#pragma unroll
    for (int kf = 0; kf < 4; ++kf) {
      const int no = kf * 32 + qo;
      v8bf bf[4];
#pragma unroll
      for (int pt = 0; pt < 4; ++pt) {
        const float* pr = Pbase + (size_t)(pt * 16 + row) * 128 + no;
        bf[pt] = cvt8(*(const float4*)pr, *(const float4*)(pr + 4));
      }
      const v8bf a0 = cvt8(*(const float4*)(Cra + no), *(const float4*)(Cra + no + 4));
      const v8bf a1 = cvt8(*(const float4*)(Crb + no), *(const float4*)(Crb + no + 4));
#pragma unroll
      for (int pt = 0; pt < 4; ++pt) {
        acc[0][pt] = __builtin_amdgcn_mfma_f32_16x16x32_bf16(a0, bf[pt], acc[0][pt], 0, 0, 0);
        acc[1][pt] = __builtin_amdgcn_mfma_f32_16x16x32_bf16(a1, bf[pt], acc[1][pt], 0, 0, 0);
      }
    }
  }

  __syncthreads();

  // ---- intra: out += cb[m,k] @ (w[k]*x[k,p]), causal ----
  {
    const float* cba = CBbase + (size_t)ma * 256;
    const float* cbb = CBbase + (size_t)mb * 256;
    const int kfa = Ta >> 1;  // last (diagonal) k-block for tile a
    const int kfb = Tb >> 1;  // last k-block for tile b (kfb >= kfa, loop bound)
    for (int kf = 0; kf <= kfb; ++kf) {
      const int ko = kf * 32 + qo;
      v8bf bf[4];
#pragma unroll
      for (int pt = 0; pt < 4; ++pt)
        bf[pt] = __builtin_bit_cast(v8bf, *(const v8u16*)&sB[(pt * 16 + row) * LDB + ko]);
      if (kf <= kfa) {
        const float4 alo = *(const float4*)(cba + ko);
        const float4 ahi = *(const float4*)(cba + ko + 4);
        v8bf a;
        if (kf == kfa) a = cvt8_mask(alo, ahi, ko, ma);
        else           a = cvt8(alo, ahi);
#pragma unroll
        for (int pt = 0; pt < 4; ++pt)
          acc[0][pt] = __builtin_amdgcn_mfma_f32_16x16x32_bf16(a, bf[pt], acc[0][pt], 0, 0, 0);
      }
      {
        const float4 alo = *(const float4*)(cbb + ko);
        const float4 ahi = *(const float4*)(cbb + ko + 4);
        v8bf a;
        if (kf == kfb) a = cvt8_mask(alo, ahi, ko, mb);
        else           a = cvt8(alo, ahi);
#pragma unroll
        for (int pt = 0; pt < 4; ++pt)
          acc[1][pt] = __builtin_amdgcn_mfma_f32_16x16x32_bf16(a, bf[pt], acc[1][pt], 0, 0, 0);
      }
    }
  }

  // ---- epilogue: out[m,p] = exp(dA[m])*acc + Dh*x[m,p] ----
  // C/D layout: col(p) = pt*16 + (lane&15), row = (lane>>4)*4 + reg
  float* Obase = outp + ((size_t)(b * 4096 + c * 256) * 32 + h) * 64;
  const int rbase = q * 4;
  const int Ts[2] = {Ta, Tb};
#pragma unroll
  for (int tt = 0; tt < 2; ++tt) {
    const int mBase = Ts[tt] * 16 + rbase;
    const float4 e4 = *(const float4*)(dAp + base_hc + mBase);
    const float ev[4] = {e4.x, e4.y, e4.z, e4.w};
#pragma unroll
    for (int r = 0; r < 4; ++r) {
      const int m = mBase + r;
      const float e = __expf(ev[r]);
      float* orow = Obase + (size_t)m * 2048;
      const float* xrow = Xbase + (size_t)m * 2048;
#pragma unroll
      for (int pt = 0; pt < 4; ++pt) {
        const int p = pt * 16 + row;
        orow[p] = acc[tt][pt][r] * e + Dh * xrow[p];
      }
    }
  }
}

extern "C" void kernel_launch(void* const* d_in, const int* in_sizes, int n_in,
                              void* d_out, int out_size, void* d_ws, size_t ws_size,
                              hipStream_t stream) {
  const float* cb = (const float*)d_in[0];
  const float* x = (const float*)d_in[1];
  const float* dt = (const float*)d_in[2];
  const float* dA = (const float*)d_in[3];
  const float* C = (const float*)d_in[4];
  const float* pv = (const float*)d_in[5];
  const float* D = (const float*)d_in[6];
  float* out = (float*)d_out;
  // grid 1024: h fastest (cb/C L2 reuse across heads), then c, b
  mamba_cs_kernel<<<dim3(1024), dim3(512), 0, stream>>>(cb, x, dt, dA, C, pv, D, out);
}

// Round 2
// 213.412 us; speedup vs baseline: 1.1421x; 1.1421x over previous
//
#include <hip/hip_runtime.h>

// MAMBA chunk scan — Round 6: restore MLP (r5 regressed: launch_bounds(512,6)
// crushed VGPR to 40 -> zero loads in flight -> latency-bound at 1.5 TB/s).
//   out[m,p] = exp(dA[m]) * ( C[m,:]@prev[p,:]^T                      (inter, K=128)
//             + sum_{k<=m} cb[m,k]*(exp(-dA[k])*dt[k]*x[k,p])         (intra, K<=256)
//             + D[h]*x[m,p]*exp(-dA[m]) )                             (diag, acc-init)
// Changes vs r5 (133us rocprof, Occ 46%, VALU 8%, VGPR 40):
//  - __launch_bounds__(512,4): 128-VGPR cap, 2 blocks/CU (LDS fits), regs for MLP.
//  - staging remapped to the MFMA C/D lane mapping: each lane loads exactly its
//    output fragment's x[m,p] (32 scalar f32) + dA/dt (2+2 float4). Those feed
//    (a) w-scaled bf16 x^T into LDS, (b) acc init = Dh*x*exp(-dA[m]) (D-term,
//    cancels the final *exp(dA[m]) exactly), (c) epilogue exp(dA) from regs.
//    -> NO epilogue x/dA reload (r5's +40MB FETCH / 16 late serial loads gone).
//  - intra loop: depth-1 software prefetch of cb float4 pairs (2x bytes in flight).
//  - XCD-chunked swizzle wg=(bid&7)*128+(bid>>3): all 32 heads of a (b,c) on one
//    XCD -> cb/C tile fetched once per XCD instead of by all 8.
// B=2 S=4096 CS=256 H=32 G=1 P=64 N=128 NC=16

typedef unsigned short u16;
typedef __bf16 v8bf __attribute__((ext_vector_type(8)));
typedef unsigned short v8u16 __attribute__((ext_vector_type(8)));
typedef float v4f __attribute__((ext_vector_type(4)));

#define LDB 264  // u16 row stride = 528B; 132 dwords == 4 mod 32 -> verified 2-way floor class

__device__ __forceinline__ unsigned pk2f(float a, float b) {
  u16 x = __builtin_bit_cast(u16, (__bf16)a);
  u16 y = __builtin_bit_cast(u16, (__bf16)b);
  return (unsigned)x | ((unsigned)y << 16);
}
__device__ __forceinline__ v8bf cvt8(float4 lo, float4 hi) {
  v8bf r;
  r[0] = (__bf16)lo.x; r[1] = (__bf16)lo.y; r[2] = (__bf16)lo.z; r[3] = (__bf16)lo.w;
  r[4] = (__bf16)hi.x; r[5] = (__bf16)hi.y; r[6] = (__bf16)hi.z; r[7] = (__bf16)hi.w;
  return r;
}
__device__ __forceinline__ v8bf cvt8_mask(float4 lo, float4 hi, int k0, int m) {
  const float av[8] = {lo.x, lo.y, lo.z, lo.w, hi.x, hi.y, hi.z, hi.w};
  v8bf r;
#pragma unroll
  for (int j = 0; j < 8; j++) r[j] = (__bf16)((k0 + j <= m) ? av[j] : 0.f);
  return r;
}

__global__ __launch_bounds__(512, 4) void mamba_cs_kernel(
    const float* __restrict__ cbp,   // (2,16,1,256,256)
    const float* __restrict__ xp,    // (2,4096,32,64)
    const float* __restrict__ dtp,   // (2,32,16,256)
    const float* __restrict__ dAp,   // (2,32,16,256)
    const float* __restrict__ Cp,    // (2,4096,1,128)
    const float* __restrict__ pvp,   // (2,16,32,64,128)
    const float* __restrict__ Dp,    // (32,)
    float* __restrict__ outp)        // (2,4096,32,64)
{
  __shared__ u16 sB[64 * LDB];  // w-scaled x^T: [p][k], 33792B

  // XCD-chunked swizzle: 1024 blocks, 8 XCDs, 128-chunk (bijective: 1024%8==0)
  const int bid0 = blockIdx.x;
  const int wg = ((bid0 & 7) << 7) | (bid0 >> 3);
  const int h = wg & 31;
  const int c = (wg >> 5) & 15;
  const int b = wg >> 9;
  const int t = threadIdx.x;
  const int lane = t & 63;
  const int wid = t >> 6;          // 0..7
  const int row = lane & 15;
  const int q = lane >> 4;
  const int qo = q * 8;

  // paired 16-row tiles for triangle balance: wave w -> tiles (w, 15-w)
  const int Ta = wid;
  const int Tb = 15 - wid;
  const int ma = Ta * 16 + row;
  const int mb = Tb * 16 + row;

  const int base_hc = ((b * 32 + h) * 16 + c) * 256;
  const float Dh = Dp[h];

  const float* CBbase = cbp + (size_t)(b * 16 + c) * 65536;
  const float* Cbase  = Cp + (size_t)(b * 4096 + c * 256) * 128;
  const float* Pbase  = pvp + (size_t)((b * 16 + c) * 32 + h) * 8192;
  const float* Xbase  = xp + ((size_t)(b * 4096 + c * 256) * 32 + h) * 64;  // k stride 2048

  v4f acc[2][4];
  float4 dAq[2];  // lane's dA rows (for epilogue exp)

  // ---- staging + acc-init, lane-exact to the C/D output mapping ----
  // lane's output fragment rows: m = T*16 + q*4 + r (r=0..3), cols p = pt*16+row.
  // Stage bf16(w[m]*x[m,p]) into sB[p][m]; init acc = Dh*x*exp(-dA[m]).
#pragma unroll
  for (int tt = 0; tt < 2; ++tt) {
    const int T = tt ? Tb : Ta;
    const int m4 = T * 16 + q * 4;
    const float4 dA4 = *(const float4*)(dAp + base_hc + m4);
    const float4 dt4 = *(const float4*)(dtp + base_hc + m4);
    dAq[tt] = dA4;
    float xv[4][4];  // [r][pt]
#pragma unroll
    for (int r = 0; r < 4; ++r) {
      const float* xr = Xbase + (size_t)(m4 + r) * 2048 + row;
#pragma unroll
      for (int pt = 0; pt < 4; ++pt) xv[r][pt] = xr[pt * 16];
    }
    const float dv[4] = {dA4.x, dA4.y, dA4.z, dA4.w};
    const float tv[4] = {dt4.x, dt4.y, dt4.z, dt4.w};
    float wi[4], w[4];
#pragma unroll
    for (int r = 0; r < 4; ++r) {
      wi[r] = __expf(-dv[r]);
      w[r] = wi[r] * tv[r];
    }
#pragma unroll
    for (int pt = 0; pt < 4; ++pt) {
      v4f a;
#pragma unroll
      for (int r = 0; r < 4; ++r) a[r] = Dh * xv[r][pt] * wi[r];
      acc[tt][pt] = a;
      // paired bf16 writes: (m4,m4+1) and (m4+2,m4+3) as dwords
      u16* srow = &sB[(pt * 16 + row) * LDB + m4];
      *(unsigned*)(srow)     = pk2f(w[0] * xv[0][pt], w[1] * xv[1][pt]);
      *(unsigned*)(srow + 2) = pk2f(w[2] * xv[2][pt], w[3] * xv[3][pt]);
    }
  }

  // ---- inter (no LDS use: runs before the barrier, hides LDS-write drain) ----
  {
    const float* Cra = Cbase + (size_t)ma * 128;
    const float* Crb = Cbase + (size_t)mb * 128;
#pragma unroll
    for (int kf = 0; kf < 4; ++kf) {
      const int no = kf * 32 + qo;
      v8bf bf[4];
#pragma unroll
      for (int pt = 0; pt < 4; ++pt) {
        const float* pr = Pbase + (size_t)(pt * 16 + row) * 128 + no;
        bf[pt] = cvt8(*(const float4*)pr, *(const float4*)(pr + 4));
      }
      const v8bf a0 = cvt8(*(const float4*)(Cra + no), *(const float4*)(Cra + no + 4));
      const v8bf a1 = cvt8(*(const float4*)(Crb + no), *(const float4*)(Crb + no + 4));
#pragma unroll
      for (int pt = 0; pt < 4; ++pt) {
        acc[0][pt] = __builtin_amdgcn_mfma_f32_16x16x32_bf16(a0, bf[pt], acc[0][pt], 0, 0, 0);
        acc[1][pt] = __builtin_amdgcn_mfma_f32_16x16x32_bf16(a1, bf[pt], acc[1][pt], 0, 0, 0);
      }
    }
  }

  __syncthreads();

  // ---- intra: acc += cb[m,k] @ (w[k]*x[k,p]), causal, depth-1 cb prefetch ----
  {
    const float* cba = CBbase + (size_t)ma * 256;
    const float* cbb = CBbase + (size_t)mb * 256;
    const int kfa = Ta >> 1;  // last (diagonal) k-block for tile a
    const int kfb = Tb >> 1;  // last k-block for tile b (kfb >= kfa)
    float4 alo = *(const float4*)(cba + qo);
    float4 ahi = *(const float4*)(cba + qo + 4);
    float4 blo = *(const float4*)(cbb + qo);
    float4 bhi = *(const float4*)(cbb + qo + 4);
    for (int kf = 0; kf <= kfb; ++kf) {
      const int ko = kf * 32 + qo;
      // prefetch next iteration's cb fragments
      float4 nalo = alo, nahi = ahi, nblo = blo, nbhi = bhi;
      if (kf < kfb) {
        const int nko = ko + 32;
        nblo = *(const float4*)(cbb + nko);
        nbhi = *(const float4*)(cbb + nko + 4);
        if (kf + 1 <= kfa) {
          nalo = *(const float4*)(cba + nko);
          nahi = *(const float4*)(cba + nko + 4);
        }
      }
      v8bf bf[4];
#pragma unroll
      for (int pt = 0; pt < 4; ++pt)
        bf[pt] = __builtin_bit_cast(v8bf, *(const v8u16*)&sB[(pt * 16 + row) * LDB + ko]);
      {
        const v8bf ab = (kf == kfb) ? cvt8_mask(blo, bhi, ko, mb) : cvt8(blo, bhi);
#pragma unroll
        for (int pt = 0; pt < 4; ++pt)
          acc[1][pt] = __builtin_amdgcn_mfma_f32_16x16x32_bf16(ab, bf[pt], acc[1][pt], 0, 0, 0);
      }
      if (kf <= kfa) {
        const v8bf aa = (kf == kfa) ? cvt8_mask(alo, ahi, ko, ma) : cvt8(alo, ahi);
#pragma unroll
        for (int pt = 0; pt < 4; ++pt)
          acc[0][pt] = __builtin_amdgcn_mfma_f32_16x16x32_bf16(aa, bf[pt], acc[0][pt], 0, 0, 0);
      }
      alo = nalo; ahi = nahi; blo = nblo; bhi = nbhi;
    }
  }

  // ---- epilogue: out[m,p] = exp(dA[m]) * acc  (D-term already inside acc) ----
  // C/D layout: col(p) = pt*16 + (lane&15), row = (lane>>4)*4 + reg
  float* Obase = outp + ((size_t)(b * 4096 + c * 256) * 32 + h) * 64;
  const int Ts[2] = {Ta, Tb};
#pragma unroll
  for (int tt = 0; tt < 2; ++tt) {
    const int mBase = Ts[tt] * 16 + q * 4;
    const float ev[4] = {dAq[tt].x, dAq[tt].y, dAq[tt].z, dAq[tt].w};
#pragma unroll
    for (int r = 0; r < 4; ++r) {
      const float e = __expf(ev[r]);
      float* orow = Obase + (size_t)(mBase + r) * 2048 + row;
#pragma unroll
      for (int pt = 0; pt < 4; ++pt) orow[pt * 16] = acc[tt][pt][r] * e;
    }
  }
}

extern "C" void kernel_launch(void* const* d_in, const int* in_sizes, int n_in,
                              void* d_out, int out_size, void* d_ws, size_t ws_size,
                              hipStream_t stream) {
  const float* cb = (const float*)d_in[0];
  const float* x = (const float*)d_in[1];
  const float* dt = (const float*)d_in[2];
  const float* dA = (const float*)d_in[3];
  const float* C = (const float*)d_in[4];
  const float* pv = (const float*)d_in[5];
  const float* D = (const float*)d_in[6];
  float* out = (float*)d_out;
  mamba_cs_kernel<<<dim3(1024), dim3(512), 0, stream>>>(cb, x, dt, dA, C, pv, D, out);
}

// Round 3
// 197.238 us; speedup vs baseline: 1.2357x; 1.0820x over previous
//
#include <hip/hip_runtime.h>

// MAMBA chunk scan — Round 7: kill per-wave cold-load chains.
//   out[m,p] = exp(dA[m]) * ( C[m,:]@prev[p,:]^T                      (inter, K=128)
//             + sum_{k<=m} cb[m,k]*(exp(-dA[k])*dt[k]*x[k,p])         (intra, K<=256)
//             + D[h]*x[m,p]*exp(-dA[m]) )                             (diag, acc-init)
// r6 post-mortem: 104us, per-wave residency ~97k cyc for ~60 loads -> serial at
// HBM latency. Worst: every one of 8 waves loaded the same 32KB prev tile from
// global (384 cold float4/block). Fixes:
//  - prev staged ONCE cooperatively into LDS as bf16 (sP, 17KB, stride 68 dw ==
//    4 mod 32 = same conflict-floor class as sB). Issued as the FIRST loads.
//    Inter B-fragments become ds_read_b128 (8x wave reuse, no cvt VALU).
//  - all 36 x/dA/dt staging loads hoisted into one batched issue (MLP burst).
//  - C(kf=0) + cb(kf=0) fragments issued BEFORE the barrier (latency hides
//    under barrier); depth-1 prefetch for C across kf and cb across intra.
//  - LDS 51.2KB -> 3 blocks/CU. launch_bounds(512,4) kept.
// B=2 S=4096 CS=256 H=32 G=1 P=64 N=128 NC=16

typedef unsigned short u16;
typedef __bf16 v8bf __attribute__((ext_vector_type(8)));
typedef unsigned short v8u16 __attribute__((ext_vector_type(8)));
typedef float v4f __attribute__((ext_vector_type(4)));

#define LDB 264  // sB u16 row stride; 132 dw == 4 mod 32 -> b128 conflict floor
#define LDP 136  // sP u16 row stride; 68 dw == 4 mod 32 -> same class; 16B-aligned rows

__device__ __forceinline__ unsigned pk2f(float a, float b) {
  u16 x = __builtin_bit_cast(u16, (__bf16)a);
  u16 y = __builtin_bit_cast(u16, (__bf16)b);
  return (unsigned)x | ((unsigned)y << 16);
}
__device__ __forceinline__ v8bf cvt8(float4 lo, float4 hi) {
  v8bf r;
  r[0] = (__bf16)lo.x; r[1] = (__bf16)lo.y; r[2] = (__bf16)lo.z; r[3] = (__bf16)lo.w;
  r[4] = (__bf16)hi.x; r[5] = (__bf16)hi.y; r[6] = (__bf16)hi.z; r[7] = (__bf16)hi.w;
  return r;
}
__device__ __forceinline__ v8bf cvt8_mask(float4 lo, float4 hi, int k0, int m) {
  const float av[8] = {lo.x, lo.y, lo.z, lo.w, hi.x, hi.y, hi.z, hi.w};
  v8bf r;
#pragma unroll
  for (int j = 0; j < 8; j++) r[j] = (__bf16)((k0 + j <= m) ? av[j] : 0.f);
  return r;
}

__global__ __launch_bounds__(512, 4) void mamba_cs_kernel(
    const float* __restrict__ cbp,   // (2,16,1,256,256)
    const float* __restrict__ xp,    // (2,4096,32,64)
    const float* __restrict__ dtp,   // (2,32,16,256)
    const float* __restrict__ dAp,   // (2,32,16,256)
    const float* __restrict__ Cp,    // (2,4096,1,128)
    const float* __restrict__ pvp,   // (2,16,32,64,128)
    const float* __restrict__ Dp,    // (32,)
    float* __restrict__ outp)        // (2,4096,32,64)
{
  __shared__ u16 sB[64 * LDB];  // w-scaled x^T bf16: [p][k], 33792B
  __shared__ u16 sP[64 * LDP];  // prev bf16: [p][n], 17408B  (total 51200B -> 3 blk/CU)

  // XCD-chunked swizzle (bijective: 1024 % 8 == 0)
  const int bid0 = blockIdx.x;
  const int wg = ((bid0 & 7) << 7) | (bid0 >> 3);
  const int h = wg & 31;
  const int c = (wg >> 5) & 15;
  const int b = wg >> 9;
  const int t = threadIdx.x;
  const int lane = t & 63;
  const int wid = t >> 6;          // 0..7
  const int row = lane & 15;
  const int q = lane >> 4;
  const int qo = q * 8;

  // paired 16-row tiles for triangle balance: wave w -> tiles (w, 15-w)
  const int Ta = wid;
  const int Tb = 15 - wid;
  const int ma = Ta * 16 + row;
  const int mb = Tb * 16 + row;

  const int base_hc = ((b * 32 + h) * 16 + c) * 256;
  const float Dh = Dp[h];

  const float* CBbase = cbp + (size_t)(b * 16 + c) * 65536;
  const float* Cbase  = Cp + (size_t)(b * 4096 + c * 256) * 128;
  const float* Pbase  = pvp + (size_t)((b * 16 + c) * 32 + h) * 8192;
  const float* Xbase  = xp + ((size_t)(b * 4096 + c * 256) * 32 + h) * 64;  // k stride 2048

  // ---- issue prev loads FIRST (coalesced, 4 float4/thread, no deps) ----
  float4 pf[4];
  {
    const float4* Pv = (const float4*)Pbase;  // 2048 float4 = 64 rows x 32
#pragma unroll
    for (int i = 0; i < 4; i++) pf[i] = Pv[i * 512 + t];
  }

  v4f acc[2][4];
  float4 dAq[2];  // lane's dA rows (for epilogue exp)

  // ---- x/dA/dt staging: batch-issue ALL loads, then transform ----
  // lane's output fragment rows: m = T*16 + q*4 + r, cols p = pt*16+row.
  {
    float4 dA4[2], dt4[2];
    float xv[2][4][4];  // [tt][r][pt]
#pragma unroll
    for (int tt = 0; tt < 2; ++tt) {
      const int T = tt ? Tb : Ta;
      const int m4 = T * 16 + q * 4;
      dA4[tt] = *(const float4*)(dAp + base_hc + m4);
      dt4[tt] = *(const float4*)(dtp + base_hc + m4);
#pragma unroll
      for (int r = 0; r < 4; ++r) {
        const float* xr = Xbase + (size_t)(m4 + r) * 2048 + row;
#pragma unroll
        for (int pt = 0; pt < 4; ++pt) xv[tt][r][pt] = xr[pt * 16];
      }
    }
#pragma unroll
    for (int tt = 0; tt < 2; ++tt) {
      const int T = tt ? Tb : Ta;
      const int m4 = T * 16 + q * 4;
      dAq[tt] = dA4[tt];
      const float dv[4] = {dA4[tt].x, dA4[tt].y, dA4[tt].z, dA4[tt].w};
      const float tv[4] = {dt4[tt].x, dt4[tt].y, dt4[tt].z, dt4[tt].w};
      float wi[4], w[4];
#pragma unroll
      for (int r = 0; r < 4; ++r) {
        wi[r] = __expf(-dv[r]);
        w[r] = wi[r] * tv[r];
      }
#pragma unroll
      for (int pt = 0; pt < 4; ++pt) {
        v4f a;
#pragma unroll
        for (int r = 0; r < 4; ++r) a[r] = Dh * xv[tt][r][pt] * wi[r];
        acc[tt][pt] = a;
        u16* srow = &sB[(pt * 16 + row) * LDB + m4];
        *(unsigned*)(srow)     = pk2f(w[0] * xv[tt][0][pt], w[1] * xv[tt][1][pt]);
        *(unsigned*)(srow + 2) = pk2f(w[2] * xv[tt][2][pt], w[3] * xv[tt][3][pt]);
      }
    }
  }

  // ---- write prev (bf16) to sP ----
#pragma unroll
  for (int i = 0; i < 4; i++) {
    const int idx = i * 512 + t;
    const int prow = idx >> 5;       // 0..63
    const int c4 = idx & 31;
    u16* s = &sP[prow * LDP + c4 * 4];
    *(unsigned*)(s)     = pk2f(pf[i].x, pf[i].y);
    *(unsigned*)(s + 2) = pk2f(pf[i].z, pf[i].w);
  }

  // ---- pre-barrier global prefetch: C (kf=0) and cb (kf=0) ----
  const float* Cra = Cbase + (size_t)ma * 128;
  const float* Crb = Cbase + (size_t)mb * 128;
  const float* cba = CBbase + (size_t)ma * 256;
  const float* cbb = CBbase + (size_t)mb * 256;
  float4 ca0 = *(const float4*)(Cra + qo);
  float4 ca1 = *(const float4*)(Cra + qo + 4);
  float4 cc0 = *(const float4*)(Crb + qo);
  float4 cc1 = *(const float4*)(Crb + qo + 4);
  float4 alo = *(const float4*)(cba + qo);
  float4 ahi = *(const float4*)(cba + qo + 4);
  float4 blo = *(const float4*)(cbb + qo);
  float4 bhi = *(const float4*)(cbb + qo + 4);

  __syncthreads();

  // ---- inter: acc += C[m,:] @ prev[p,:]^T, B from sP (LDS), depth-1 C prefetch ----
#pragma unroll
  for (int kf = 0; kf < 4; ++kf) {
    const int no = kf * 32 + qo;
    float4 nca0 = ca0, nca1 = ca1, ncc0 = cc0, ncc1 = cc1;
    if (kf < 3) {
      const int nn = no + 32;
      nca0 = *(const float4*)(Cra + nn);
      nca1 = *(const float4*)(Cra + nn + 4);
      ncc0 = *(const float4*)(Crb + nn);
      ncc1 = *(const float4*)(Crb + nn + 4);
    }
    v8bf bf[4];
#pragma unroll
    for (int pt = 0; pt < 4; ++pt)
      bf[pt] = __builtin_bit_cast(v8bf, *(const v8u16*)&sP[(pt * 16 + row) * LDP + no]);
    const v8bf a0 = cvt8(ca0, ca1);
    const v8bf a1 = cvt8(cc0, cc1);
#pragma unroll
    for (int pt = 0; pt < 4; ++pt) {
      acc[0][pt] = __builtin_amdgcn_mfma_f32_16x16x32_bf16(a0, bf[pt], acc[0][pt], 0, 0, 0);
      acc[1][pt] = __builtin_amdgcn_mfma_f32_16x16x32_bf16(a1, bf[pt], acc[1][pt], 0, 0, 0);
    }
    ca0 = nca0; ca1 = nca1; cc0 = ncc0; cc1 = ncc1;
  }

  // ---- intra: acc += cb[m,k] @ (w[k]*x[k,p]), causal, depth-1 cb prefetch ----
  {
    const int kfa = Ta >> 1;  // last (diagonal) k-block for tile a
    const int kfb = Tb >> 1;  // last k-block for tile b (kfb >= kfa)
    for (int kf = 0; kf <= kfb; ++kf) {
      const int ko = kf * 32 + qo;
      float4 nalo = alo, nahi = ahi, nblo = blo, nbhi = bhi;
      if (kf < kfb) {
        const int nko = ko + 32;
        nblo = *(const float4*)(cbb + nko);
        nbhi = *(const float4*)(cbb + nko + 4);
        if (kf + 1 <= kfa) {
          nalo = *(const float4*)(cba + nko);
          nahi = *(const float4*)(cba + nko + 4);
        }
      }
      v8bf bf[4];
#pragma unroll
      for (int pt = 0; pt < 4; ++pt)
        bf[pt] = __builtin_bit_cast(v8bf, *(const v8u16*)&sB[(pt * 16 + row) * LDB + ko]);
      {
        const v8bf ab = (kf == kfb) ? cvt8_mask(blo, bhi, ko, mb) : cvt8(blo, bhi);
#pragma unroll
        for (int pt = 0; pt < 4; ++pt)
          acc[1][pt] = __builtin_amdgcn_mfma_f32_16x16x32_bf16(ab, bf[pt], acc[1][pt], 0, 0, 0);
      }
      if (kf <= kfa) {
        const v8bf aa = (kf == kfa) ? cvt8_mask(alo, ahi, ko, ma) : cvt8(alo, ahi);
#pragma unroll
        for (int pt = 0; pt < 4; ++pt)
          acc[0][pt] = __builtin_amdgcn_mfma_f32_16x16x32_bf16(aa, bf[pt], acc[0][pt], 0, 0, 0);
      }
      alo = nalo; ahi = nahi; blo = nblo; bhi = nbhi;
    }
  }

  // ---- epilogue: out[m,p] = exp(dA[m]) * acc  (D-term already inside acc) ----
  // C/D layout: col(p) = pt*16 + (lane&15), row = (lane>>4)*4 + reg
  float* Obase = outp + ((size_t)(b * 4096 + c * 256) * 32 + h) * 64;
  const int Ts[2] = {Ta, Tb};
#pragma unroll
  for (int tt = 0; tt < 2; ++tt) {
    const int mBase = Ts[tt] * 16 + q * 4;
    const float ev[4] = {dAq[tt].x, dAq[tt].y, dAq[tt].z, dAq[tt].w};
#pragma unroll
    for (int r = 0; r < 4; ++r) {
      const float e = __expf(ev[r]);
      float* orow = Obase + (size_t)(mBase + r) * 2048 + row;
#pragma unroll
      for (int pt = 0; pt < 4; ++pt) orow[pt * 16] = acc[tt][pt][r] * e;
    }
  }
}

extern "C" void kernel_launch(void* const* d_in, const int* in_sizes, int n_in,
                              void* d_out, int out_size, void* d_ws, size_t ws_size,
                              hipStream_t stream) {
  const float* cb = (const float*)d_in[0];
  const float* x = (const float*)d_in[1];
  const float* dt = (const float*)d_in[2];
  const float* dA = (const float*)d_in[3];
  const float* C = (const float*)d_in[4];
  const float* pv = (const float*)d_in[5];
  const float* D = (const float*)d_in[6];
  float* out = (float*)d_out;
  mamba_cs_kernel<<<dim3(1024), dim3(512), 0, stream>>>(cb, x, dt, dA, C, pv, D, out);
}

// Round 4
// 176.356 us; speedup vs baseline: 1.3820x; 1.1184x over previous
//
#include <hip/hip_runtime.h>

// MAMBA chunk scan — Round 8: exploit G=1 head-invariance of cb/C.
//   out[m,p] = exp(dA[m]) * ( C[m,:]@prev[p,:]^T                      (inter, K=128)
//             + sum_{k<=m} cb[m,k]*(exp(-dA[k])*dt[k]*x[k,p])         (intra, K<=256)
//             + D[h]*x[m,p]*exp(-dA[m]) )                             (diag, acc-init)
// r7 post-mortem: 85us, VGPR=64 (cap 128) -> compiler serialized load batches
// again; per-wave residency 75k cyc. Key structural fact: with G=1 the bf16
// A-fragments (cb masked, C) are IDENTICAL for all 32 heads.
// New shape: block = (b,c,4-head group), grid 256 (1 block/CU), 512 thr.
//  - cb/C A-frags loaded ONCE -> persistent v8bf regs (~80 VGPR). Per-head
//    compute phase has ZERO global loads (ds_read_b128 + MFMA only).
//  - per head: stage x*w -> sB, prev(bf16) -> sP; next head's stage loads
//    issued right after the barrier, hidden under current compute (T14).
//    Ping-pong stage buffers with fully-static indices (rule #20).
//  - launch_bounds(512,2): 256-VGPR cap; persistence forces real allocation.
//  - XCD swizzle chunk=32: each XCD owns 4 full (b,c) groups -> cb/C fetched
//    once per XCD L2.
// B=2 S=4096 CS=256 H=32 G=1 P=64 N=128 NC=16

typedef unsigned short u16;
typedef __bf16 v8bf __attribute__((ext_vector_type(8)));
typedef unsigned short v8u16 __attribute__((ext_vector_type(8)));
typedef float v4f __attribute__((ext_vector_type(4)));

#define LDB 264  // sB u16 row stride; 132 dw == 4 mod 32 (verified conflict-floor class)
#define LDP 136  // sP u16 row stride; 68 dw == 4 mod 32

__device__ __forceinline__ unsigned pk2f(float a, float b) {
  u16 x = __builtin_bit_cast(u16, (__bf16)a);
  u16 y = __builtin_bit_cast(u16, (__bf16)b);
  return (unsigned)x | ((unsigned)y << 16);
}
__device__ __forceinline__ v8bf cvt8(float4 lo, float4 hi) {
  v8bf r;
  r[0] = (__bf16)lo.x; r[1] = (__bf16)lo.y; r[2] = (__bf16)lo.z; r[3] = (__bf16)lo.w;
  r[4] = (__bf16)hi.x; r[5] = (__bf16)hi.y; r[6] = (__bf16)hi.z; r[7] = (__bf16)hi.w;
  return r;
}
__device__ __forceinline__ v8bf cvt8_mask(float4 lo, float4 hi, int k0, int m) {
  const float av[8] = {lo.x, lo.y, lo.z, lo.w, hi.x, hi.y, hi.z, hi.w};
  v8bf r;
#pragma unroll
  for (int j = 0; j < 8; j++) r[j] = (__bf16)((k0 + j <= m) ? av[j] : 0.f);
  return r;
}

struct SR {  // per-head stage registers (ping-pong pair, static-indexed only)
  float4 pf[4];            // prev, coalesced
  float4 dA4[2], dt4[2];   // lane's m-rows
  float xv[2][4][4];       // x[m,p] in C/D fragment layout [tt][r][pt]
};

__global__ __launch_bounds__(512, 2) void mamba_cs_kernel(
    const float* __restrict__ cbp,   // (2,16,1,256,256)
    const float* __restrict__ xp,    // (2,4096,32,64)
    const float* __restrict__ dtp,   // (2,32,16,256)
    const float* __restrict__ dAp,   // (2,32,16,256)
    const float* __restrict__ Cp,    // (2,4096,1,128)
    const float* __restrict__ pvp,   // (2,16,32,64,128)
    const float* __restrict__ Dp,    // (32,)
    float* __restrict__ outp)        // (2,4096,32,64)
{
  __shared__ u16 sB[64 * LDB];  // w-scaled x^T bf16: [p][k], 33792B
  __shared__ u16 sP[64 * LDP];  // prev bf16: [p][n], 17408B  (51200B total)

  // XCD-chunked swizzle, chunk 32 (bijective: 256 % 8 == 0)
  const int bid0 = blockIdx.x;
  const int wg = ((bid0 & 7) << 5) | (bid0 >> 3);
  const int hg = wg & 7;            // 4-head group
  const int c = (wg >> 3) & 15;
  const int b = wg >> 7;
  const int h0 = hg * 4;

  const int t = threadIdx.x;
  const int lane = t & 63;
  const int wid = t >> 6;           // 0..7
  const int row = lane & 15;
  const int q = lane >> 4;
  const int qo = q * 8;

  // paired 16-row tiles for triangle balance: wave w -> tiles (w, 15-w)
  const int Ta = wid;
  const int Tb = 15 - wid;
  const int ma = Ta * 16 + row;
  const int mb = Tb * 16 + row;
  const int kfa = Ta >> 1;
  const int kfb = Tb >> 1;

  const float* CBbase = cbp + (size_t)(b * 16 + c) * 65536;
  const float* Cbase  = Cp + (size_t)(b * 4096 + c * 256) * 128;

  // ---- persistent h-independent A-fragments (loaded once) ----
  const float* Cra = Cbase + (size_t)ma * 128;
  const float* Crb = Cbase + (size_t)mb * 128;
  const float* cba = CBbase + (size_t)ma * 256;
  const float* cbb = CBbase + (size_t)mb * 256;

  v8bf Ca[4], Cb2[4];  // inter A-frags, tiles a/b
  v8bf Aa[4], Ab[8];   // intra A-frags (masked at diagonal), tiles a/b
#pragma unroll
  for (int kf = 0; kf < 4; ++kf) {
    const int no = kf * 32 + qo;
    Ca[kf]  = cvt8(*(const float4*)(Cra + no), *(const float4*)(Cra + no + 4));
    Cb2[kf] = cvt8(*(const float4*)(Crb + no), *(const float4*)(Crb + no + 4));
  }
#pragma unroll
  for (int kf = 0; kf < 4; ++kf)
    if (kf <= kfa) {
      const int ko = kf * 32 + qo;
      const float4 lo = *(const float4*)(cba + ko);
      const float4 hi = *(const float4*)(cba + ko + 4);
      Aa[kf] = (kf == kfa) ? cvt8_mask(lo, hi, ko, ma) : cvt8(lo, hi);
    }
#pragma unroll
  for (int kf = 0; kf < 8; ++kf)
    if (kf <= kfb) {
      const int ko = kf * 32 + qo;
      const float4 lo = *(const float4*)(cbb + ko);
      const float4 hi = *(const float4*)(cbb + ko + 4);
      Ab[kf] = (kf == kfb) ? cvt8_mask(lo, hi, ko, mb) : cvt8(lo, hi);
    }

  v4f acc[2][4];
  float4 dAq[2];

  auto stage_load = [&](int h, SR& R) {
    const float4* Pv = (const float4*)(pvp + (size_t)((b * 16 + c) * 32 + h) * 8192);
#pragma unroll
    for (int i = 0; i < 4; i++) R.pf[i] = Pv[i * 512 + t];
    const int bhc = ((b * 32 + h) * 16 + c) * 256;
    const float* Xb = xp + ((size_t)(b * 4096 + c * 256) * 32 + h) * 64;
#pragma unroll
    for (int tt = 0; tt < 2; ++tt) {
      const int m4 = (tt ? Tb : Ta) * 16 + q * 4;
      R.dA4[tt] = *(const float4*)(dAp + bhc + m4);
      R.dt4[tt] = *(const float4*)(dtp + bhc + m4);
#pragma unroll
      for (int r = 0; r < 4; ++r) {
        const float* xr = Xb + (size_t)(m4 + r) * 2048 + row;
#pragma unroll
        for (int pt = 0; pt < 4; ++pt) R.xv[tt][r][pt] = xr[pt * 16];
      }
    }
  };

  auto commit = [&](SR& R, float Dh) {
    // prev -> sP (bf16)
#pragma unroll
    for (int i = 0; i < 4; i++) {
      const int idx = i * 512 + t, prow = idx >> 5, c4 = idx & 31;
      u16* s = &sP[prow * LDP + c4 * 4];
      *(unsigned*)(s)     = pk2f(R.pf[i].x, R.pf[i].y);
      *(unsigned*)(s + 2) = pk2f(R.pf[i].z, R.pf[i].w);
    }
    // x*w -> sB, acc init = Dh*x*exp(-dA[m])
#pragma unroll
    for (int tt = 0; tt < 2; ++tt) {
      const int m4 = (tt ? Tb : Ta) * 16 + q * 4;
      dAq[tt] = R.dA4[tt];
      const float dv[4] = {R.dA4[tt].x, R.dA4[tt].y, R.dA4[tt].z, R.dA4[tt].w};
      const float tv[4] = {R.dt4[tt].x, R.dt4[tt].y, R.dt4[tt].z, R.dt4[tt].w};
      float wi[4], w[4];
#pragma unroll
      for (int r = 0; r < 4; ++r) {
        wi[r] = __expf(-dv[r]);
        w[r] = wi[r] * tv[r];
      }
#pragma unroll
      for (int pt = 0; pt < 4; ++pt) {
        v4f a;
#pragma unroll
        for (int r = 0; r < 4; ++r) a[r] = Dh * R.xv[tt][r][pt] * wi[r];
        acc[tt][pt] = a;
        u16* srow = &sB[(pt * 16 + row) * LDB + m4];
        *(unsigned*)(srow)     = pk2f(w[0] * R.xv[tt][0][pt], w[1] * R.xv[tt][1][pt]);
        *(unsigned*)(srow + 2) = pk2f(w[2] * R.xv[tt][2][pt], w[3] * R.xv[tt][3][pt]);
      }
    }
  };

  auto compute = [&]() {
    // inter: A = persistent C-frags, B = sP
#pragma unroll
    for (int kf = 0; kf < 4; ++kf) {
      const int no = kf * 32 + qo;
      v8bf bf[4];
#pragma unroll
      for (int pt = 0; pt < 4; ++pt)
        bf[pt] = __builtin_bit_cast(v8bf, *(const v8u16*)&sP[(pt * 16 + row) * LDP + no]);
#pragma unroll
      for (int pt = 0; pt < 4; ++pt) {
        acc[0][pt] = __builtin_amdgcn_mfma_f32_16x16x32_bf16(Ca[kf], bf[pt], acc[0][pt], 0, 0, 0);
        acc[1][pt] = __builtin_amdgcn_mfma_f32_16x16x32_bf16(Cb2[kf], bf[pt], acc[1][pt], 0, 0, 0);
      }
    }
    // intra: A = persistent cb-frags, B = sB, causal
#pragma unroll
    for (int kf = 0; kf < 8; ++kf) {
      if (kf <= kfb) {
        const int ko = kf * 32 + qo;
        v8bf bf[4];
#pragma unroll
        for (int pt = 0; pt < 4; ++pt)
          bf[pt] = __builtin_bit_cast(v8bf, *(const v8u16*)&sB[(pt * 16 + row) * LDB + ko]);
#pragma unroll
        for (int pt = 0; pt < 4; ++pt)
          acc[1][pt] = __builtin_amdgcn_mfma_f32_16x16x32_bf16(Ab[kf], bf[pt], acc[1][pt], 0, 0, 0);
        if (kf <= kfa) {
#pragma unroll
          for (int pt = 0; pt < 4; ++pt)
            acc[0][pt] = __builtin_amdgcn_mfma_f32_16x16x32_bf16(Aa[kf], bf[pt], acc[0][pt], 0, 0, 0);
        }
      }
    }
  };

  auto epilogue = [&](int h) {
    float* Ob = outp + ((size_t)(b * 4096 + c * 256) * 32 + h) * 64;
#pragma unroll
    for (int tt = 0; tt < 2; ++tt) {
      const int mBase = (tt ? Tb : Ta) * 16 + q * 4;
      const float ev[4] = {dAq[tt].x, dAq[tt].y, dAq[tt].z, dAq[tt].w};
#pragma unroll
      for (int r = 0; r < 4; ++r) {
        const float e = __expf(ev[r]);
        float* orow = Ob + (size_t)(mBase + r) * 2048 + row;
#pragma unroll
        for (int pt = 0; pt < 4; ++pt) orow[pt * 16] = acc[tt][pt][r] * e;
      }
    }
  };

  const float D0 = Dp[h0], D1 = Dp[h0 + 1], D2 = Dp[h0 + 2], D3 = Dp[h0 + 3];

  SR RA, RB;
  stage_load(h0, RA);

  // h0
  commit(RA, D0);
  __syncthreads();
  stage_load(h0 + 1, RB);   // hidden under compute
  compute();
  epilogue(h0);
  __syncthreads();

  // h1
  commit(RB, D1);
  __syncthreads();
  stage_load(h0 + 2, RA);
  compute();
  epilogue(h0 + 1);
  __syncthreads();

  // h2
  commit(RA, D2);
  __syncthreads();
  stage_load(h0 + 3, RB);
  compute();
  epilogue(h0 + 2);
  __syncthreads();

  // h3
  commit(RB, D3);
  __syncthreads();
  compute();
  epilogue(h0 + 3);
}

extern "C" void kernel_launch(void* const* d_in, const int* in_sizes, int n_in,
                              void* d_out, int out_size, void* d_ws, size_t ws_size,
                              hipStream_t stream) {
  const float* cb = (const float*)d_in[0];
  const float* x = (const float*)d_in[1];
  const float* dt = (const float*)d_in[2];
  const float* dA = (const float*)d_in[3];
  const float* C = (const float*)d_in[4];
  const float* pv = (const float*)d_in[5];
  const float* D = (const float*)d_in[6];
  float* out = (float*)d_out;
  // grid 256: block = (b,c,hg4); 1 block/CU
  mamba_cs_kernel<<<dim3(256), dim3(512), 0, stream>>>(cb, x, dt, dA, C, pv, D, out);
}